// Round 1
// baseline (98.712 us; speedup 1.0000x reference)
//
#include <hip/hip_runtime.h>

#define K_CODES 32768
#define N_PTS   8192
#define NC      16                 // code chunks
#define CHUNK   (K_CODES / NC)     // 2048 codes per chunk
#define NPB     (N_PTS / 256)      // 32 point blocks

// ---------------- K0: bnorm[k] = ||E_k||^2 with exact fp32 sequential rounding
__global__ __launch_bounds__(256) void k_bnorm(const float* __restrict__ E,
                                               float* __restrict__ bnorm) {
#pragma clang fp contract(off)
    int k = blockIdx.x * 256 + threadIdx.x;
    float4 e = ((const float4*)E)[k];
    bnorm[k] = ((e.x * e.x + e.y * e.y) + e.z * e.z) + e.w * e.w;
}

// ---------------- K1: partial argmin over one code chunk for 256 points
__global__ __launch_bounds__(256) void k_dist(const float* __restrict__ x,
                                              const float* __restrict__ E,
                                              const float* __restrict__ bnorm,
                                              float* __restrict__ dbest,
                                              int* __restrict__ kbest) {
#pragma clang fp contract(off)
    __shared__ float4 eL[CHUNK];
    __shared__ float  bL[CHUNK];
    const int chunk = blockIdx.x;      // 0..NC-1
    const int pblk  = blockIdx.y;      // 0..NPB-1
    const int tid   = threadIdx.x;
    const int kbase = chunk * CHUNK;

    for (int i = tid; i < CHUNK; i += 256) {
        eL[i] = ((const float4*)E)[kbase + i];
        bL[i] = bnorm[kbase + i];
    }
    __syncthreads();

    const int p = pblk * 256 + tid;
    const int t = p >> 12;             // 0..1
    const int s = p & 4095;            // h*64+w
    const int xb = t * 16384 + s;
    const float x0 = x[xb];
    const float x1 = x[xb + 4096];
    const float x2 = x[xb + 8192];
    const float x3 = x[xb + 12288];
    // a = ((x0^2 + x1^2) + x2^2) + x3^2, each square individually rounded
    const float a = ((x0 * x0 + x1 * x1) + x2 * x2) + x3 * x3;

    float bd = 3.402823466e38f;
    int   bk = 0;
    for (int j = 0; j < CHUNK; ++j) {
        float4 e = eL[j];
        // BLAS-style fp32 FMA accumulation chain
        float m = __builtin_fmaf(x3, e.w,
                   __builtin_fmaf(x2, e.z,
                    __builtin_fmaf(x1, e.y, x0 * e.x)));
        float d = (a + bL[j]) - 2.0f * m;
        if (d < bd) { bd = d; bk = kbase + j; }   // strict <: earliest k wins ties
    }
    dbest[chunk * N_PTS + p] = bd;
    kbest[chunk * N_PTS + p] = bk;
}

// ---------------- K2: merge chunks, gather, z_q_st, per-block loss partial
__global__ __launch_bounds__(256) void k_final(const float* __restrict__ x,
                                               const float* __restrict__ E,
                                               const float* __restrict__ dbest,
                                               const int* __restrict__ kbest,
                                               float* __restrict__ out,
                                               double* __restrict__ partials) {
#pragma clang fp contract(off)
    const int tid = threadIdx.x;
    const int p   = blockIdx.x * 256 + tid;
    const int t   = p >> 12;
    const int s   = p & 4095;

    float bd = 3.402823466e38f;
    int   bk = 0;
    for (int c2 = 0; c2 < NC; ++c2) {          // increasing k ranges
        float d = dbest[c2 * N_PTS + p];
        int   k = kbest[c2 * N_PTS + p];
        if (d < bd) { bd = d; bk = k; }        // strict <: earliest chunk kept
    }

    float4 e = ((const float4*)E)[bk];
    float ev[4] = {e.x, e.y, e.z, e.w};
    double ls = 0.0;
    const int xb = t * 16384 + s;
    for (int ch = 0; ch < 4; ++ch) {
        int idx = xb + ch * 4096;
        float xv   = x[idx];
        float diff = ev[ch] - xv;              // fl(z_q - x)
        float sq   = diff * diff;              // fl(diff^2)
        out[idx]   = xv + diff;                // z_q_st = fl(x + fl(z_q - x))
        ls += (double)sq;
    }
    out[32769 + p] = (float)bk;                // codes as float

    __shared__ double sred[256];
    sred[tid] = ls;
    __syncthreads();
    for (int o = 128; o > 0; o >>= 1) {
        if (tid < o) sred[tid] += sred[tid + o];
        __syncthreads();
    }
    if (tid == 0) partials[blockIdx.x] = sred[0];
}

// ---------------- K3: finalize qloss
__global__ void k_loss(const double* __restrict__ partials,
                       float* __restrict__ out) {
#pragma clang fp contract(off)
    if (threadIdx.x == 0 && blockIdx.x == 0) {
        double sum = 0.0;
        for (int i = 0; i < NPB; ++i) sum += partials[i];
        float mu = (float)(sum * (1.0 / 32768.0));   // /32768 exact scale
        float q  = mu + 0.1f * mu;                   // mean1 + BETA*mean2 (bitwise equal means)
        out[32768] = q;
    }
}

extern "C" void kernel_launch(void* const* d_in, const int* in_sizes, int n_in,
                              void* d_out, int out_size, void* d_ws, size_t ws_size,
                              hipStream_t stream) {
    const float* x = (const float*)d_in[0];   // (1,2,4,64,64)
    const float* E = (const float*)d_in[1];   // (32768,4)
    float* out = (float*)d_out;               // 40961 floats

    char* ws = (char*)d_ws;
    double* partials = (double*)ws;                              // 32 doubles (256 B)
    float*  bnorm    = (float*)(ws + 256);                       // 128 KB
    float*  dbest    = (float*)(ws + 256 + 131072);              // 512 KB
    int*    kbest    = (int*)  (ws + 256 + 131072 + 524288);     // 512 KB

    k_bnorm<<<K_CODES / 256, 256, 0, stream>>>(E, bnorm);
    dim3 g1(NC, NPB);
    k_dist<<<g1, 256, 0, stream>>>(x, E, bnorm, dbest, kbest);
    k_final<<<NPB, 256, 0, stream>>>(x, E, dbest, kbest, out, partials);
    k_loss<<<1, 64, 0, stream>>>(partials, out);
}

// Round 2
// 83.276 us; speedup vs baseline: 1.1854x; 1.1854x over previous
//
#include <hip/hip_runtime.h>

#define K_CODES 32768
#define N_PTS   8192
#define NC      32                 // code chunks
#define CHUNK   (K_CODES / NC)     // 1024 codes per chunk
#define NPB     (N_PTS / 256)      // 32 point blocks

typedef float v2f __attribute__((ext_vector_type(2)));

// ---------------- K0: bnorm[k] = ||E_k||^2 with exact fp32 sequential rounding
__global__ __launch_bounds__(256) void k_bnorm(const float* __restrict__ E,
                                               float* __restrict__ bnorm) {
#pragma clang fp contract(off)
    int k = blockIdx.x * 256 + threadIdx.x;
    float4 e = ((const float4*)E)[k];
    bnorm[k] = ((e.x * e.x + e.y * e.y) + e.z * e.z) + e.w * e.w;
}

// ---------------- K1: partial argmin over one code chunk for 256 points
__global__ __launch_bounds__(256, 4) void k_dist(const float* __restrict__ x,
                                                 const float* __restrict__ E,
                                                 const float* __restrict__ bnorm,
                                                 float* __restrict__ dbest,
                                                 int* __restrict__ kbest) {
#pragma clang fp contract(off)
    // SoA LDS: broadcast-friendly, feeds packed f32 pairs directly
    __shared__ float exL[CHUNK];
    __shared__ float eyL[CHUNK];
    __shared__ float ezL[CHUNK];
    __shared__ float ewL[CHUNK];
    __shared__ float bL[CHUNK];

    const int chunk = blockIdx.x;      // 0..NC-1
    const int pblk  = blockIdx.y;      // 0..NPB-1
    const int tid   = threadIdx.x;
    const int kbase = chunk * CHUNK;

    for (int i = tid; i < CHUNK; i += 256) {
        float4 e = ((const float4*)E)[kbase + i];
        exL[i] = e.x; eyL[i] = e.y; ezL[i] = e.z; ewL[i] = e.w;
        bL[i]  = bnorm[kbase + i];
    }
    __syncthreads();

    const int p = pblk * 256 + tid;
    const int t = p >> 12;             // 0..1
    const int s = p & 4095;            // h*64+w
    const int xb = t * 16384 + s;
    const float x0 = x[xb];
    const float x1 = x[xb + 4096];
    const float x2 = x[xb + 8192];
    const float x3 = x[xb + 12288];
    // a = ((x0^2 + x1^2) + x2^2) + x3^2, each square individually rounded
    const float a = ((x0 * x0 + x1 * x1) + x2 * x2) + x3 * x3;

    const v2f X0 = {x0, x0}, X1 = {x1, x1}, X2 = {x2, x2}, X3 = {x3, x3};
    const v2f Av = {a, a};
    const v2f M2 = {-2.0f, -2.0f};

    float bd = 3.402823466e38f;
    int   bk = 0;

    for (int jj = 0; jj < CHUNK; jj += 4) {
        float4 vx = *(const float4*)&exL[jj];
        float4 vy = *(const float4*)&eyL[jj];
        float4 vz = *(const float4*)&ezL[jj];
        float4 vw = *(const float4*)&ewL[jj];
        float4 vb = *(const float4*)&bL[jj];

        // pair A: codes jj, jj+1
        v2f eax = {vx.x, vx.y}, eay = {vy.x, vy.y}, eaz = {vz.x, vz.y}, eaw = {vw.x, vw.y};
        v2f ba  = {vb.x, vb.y};
        v2f ma = __builtin_elementwise_fma(X3, eaw,
                  __builtin_elementwise_fma(X2, eaz,
                   __builtin_elementwise_fma(X1, eay, X0 * eax)));
        v2f ta = Av + ba;
        // fma(-2,m,t) == t - fl(2m) bitwise: fl(2m) exact, both round once
        v2f da = __builtin_elementwise_fma(M2, ma, ta);

        // pair B: codes jj+2, jj+3
        v2f ebx = {vx.z, vx.w}, eby = {vy.z, vy.w}, ebz = {vz.z, vz.w}, ebw = {vw.z, vw.w};
        v2f bb  = {vb.z, vb.w};
        v2f mb = __builtin_elementwise_fma(X3, ebw,
                  __builtin_elementwise_fma(X2, ebz,
                   __builtin_elementwise_fma(X1, eby, X0 * ebx)));
        v2f tb = Av + bb;
        v2f db = __builtin_elementwise_fma(M2, mb, tb);

        // ordered strict-< selects: earliest k wins ties
        bool c0 = da.x < bd; bd = c0 ? da.x : bd; bk = c0 ? (kbase + jj)     : bk;
        bool c1 = da.y < bd; bd = c1 ? da.y : bd; bk = c1 ? (kbase + jj + 1) : bk;
        bool c2 = db.x < bd; bd = c2 ? db.x : bd; bk = c2 ? (kbase + jj + 2) : bk;
        bool c3 = db.y < bd; bd = c3 ? db.y : bd; bk = c3 ? (kbase + jj + 3) : bk;
    }
    dbest[chunk * N_PTS + p] = bd;
    kbest[chunk * N_PTS + p] = bk;
}

// ---------------- K2: merge chunks, gather, z_q_st, per-block loss partial
__global__ __launch_bounds__(256) void k_final(const float* __restrict__ x,
                                               const float* __restrict__ E,
                                               const float* __restrict__ dbest,
                                               const int* __restrict__ kbest,
                                               float* __restrict__ out,
                                               double* __restrict__ partials) {
#pragma clang fp contract(off)
    const int tid = threadIdx.x;
    const int p   = blockIdx.x * 256 + tid;
    const int t   = p >> 12;
    const int s   = p & 4095;

    float bd = 3.402823466e38f;
    int   bk = 0;
    for (int c2 = 0; c2 < NC; ++c2) {          // increasing k ranges
        float d = dbest[c2 * N_PTS + p];
        int   k = kbest[c2 * N_PTS + p];
        if (d < bd) { bd = d; bk = k; }        // strict <: earliest chunk kept
    }

    float4 e = ((const float4*)E)[bk];
    float ev[4] = {e.x, e.y, e.z, e.w};
    double ls = 0.0;
    const int xb = t * 16384 + s;
    for (int ch = 0; ch < 4; ++ch) {
        int idx = xb + ch * 4096;
        float xv   = x[idx];
        float diff = ev[ch] - xv;              // fl(z_q - x)
        float sq   = diff * diff;              // fl(diff^2)
        out[idx]   = xv + diff;                // z_q_st = fl(x + fl(z_q - x))
        ls += (double)sq;
    }
    out[32769 + p] = (float)bk;                // codes as float

    __shared__ double sred[256];
    sred[tid] = ls;
    __syncthreads();
    for (int o = 128; o > 0; o >>= 1) {
        if (tid < o) sred[tid] += sred[tid + o];
        __syncthreads();
    }
    if (tid == 0) partials[blockIdx.x] = sred[0];
}

// ---------------- K3: finalize qloss
__global__ void k_loss(const double* __restrict__ partials,
                       float* __restrict__ out) {
#pragma clang fp contract(off)
    if (threadIdx.x == 0 && blockIdx.x == 0) {
        double sum = 0.0;
        for (int i = 0; i < NPB; ++i) sum += partials[i];
        float mu = (float)(sum * (1.0 / 32768.0));   // /32768 exact scale
        float q  = mu + 0.1f * mu;                   // mean1 + BETA*mean2 (bitwise equal means)
        out[32768] = q;
    }
}

extern "C" void kernel_launch(void* const* d_in, const int* in_sizes, int n_in,
                              void* d_out, int out_size, void* d_ws, size_t ws_size,
                              hipStream_t stream) {
    const float* x = (const float*)d_in[0];   // (1,2,4,64,64)
    const float* E = (const float*)d_in[1];   // (32768,4)
    float* out = (float*)d_out;               // 40961 floats

    char* ws = (char*)d_ws;
    double* partials = (double*)ws;                              // 256 B
    float*  bnorm    = (float*)(ws + 256);                       // 128 KB
    float*  dbest    = (float*)(ws + 256 + 131072);              // 1 MB
    int*    kbest    = (int*)  (ws + 256 + 131072 + 1048576);    // 1 MB

    k_bnorm<<<K_CODES / 256, 256, 0, stream>>>(E, bnorm);
    dim3 g1(NC, NPB);
    k_dist<<<g1, 256, 0, stream>>>(x, E, bnorm, dbest, kbest);
    k_final<<<NPB, 256, 0, stream>>>(x, E, dbest, kbest, out, partials);
    k_loss<<<1, 64, 0, stream>>>(partials, out);
}

// Round 3
// 72.575 us; speedup vs baseline: 1.3601x; 1.1474x over previous
//
#include <hip/hip_runtime.h>

#define K_CODES 32768
#define N_PTS   8192
#define NC      32                 // code chunks
#define CHUNK   (K_CODES / NC)     // 1024 codes per chunk
#define NPB     (N_PTS / 256)      // 32 point blocks (k_dist)

typedef float v2f __attribute__((ext_vector_type(2)));

// Packed fp32 ops (CDNA2+): IEEE round-to-nearest per 32-bit half — bit-identical
// to the scalar v_mul/v_fma chain verified in R1/R2.
__device__ __forceinline__ v2f pk_mul(v2f a, v2f b) {
    v2f d; asm("v_pk_mul_f32 %0, %1, %2" : "=v"(d) : "v"(a), "v"(b)); return d;
}
__device__ __forceinline__ v2f pk_fma(v2f a, v2f b, v2f c) {
    v2f d; asm("v_pk_fma_f32 %0, %1, %2, %3" : "=v"(d) : "v"(a), "v"(b), "v"(c)); return d;
}
__device__ __forceinline__ v2f pk_add(v2f a, v2f b) {
    v2f d; asm("v_pk_add_f32 %0, %1, %2" : "=v"(d) : "v"(a), "v"(b)); return d;
}
__device__ __forceinline__ float min3f(float a, float b, float c) {
    float d; asm("v_min3_f32 %0, %1, %2, %3" : "=v"(d) : "v"(a), "v"(b), "v"(c)); return d;
}

// ---------------- K1: partial argmin over one code chunk for 256 points
__global__ __launch_bounds__(256) void k_dist(const float* __restrict__ x,
                                              const float* __restrict__ E,
                                              float* __restrict__ dbest,
                                              int* __restrict__ kbest) {
#pragma clang fp contract(off)
    __shared__ float exL[CHUNK];
    __shared__ float eyL[CHUNK];
    __shared__ float ezL[CHUNK];
    __shared__ float ewL[CHUNK];
    __shared__ float bL[CHUNK];

    const int chunk = blockIdx.x;      // 0..NC-1
    const int pblk  = blockIdx.y;      // 0..NPB-1
    const int tid   = threadIdx.x;
    const int kbase = chunk * CHUNK;

    // Stage SoA + fused bnorm (squares individually rounded, sequential adds:
    // matches jnp.sum(E*E, axis=1) as verified in R1)
    for (int i = tid; i < CHUNK; i += 256) {
        float4 e = ((const float4*)E)[kbase + i];
        exL[i] = e.x; eyL[i] = e.y; ezL[i] = e.z; ewL[i] = e.w;
        bL[i]  = ((e.x * e.x + e.y * e.y) + e.z * e.z) + e.w * e.w;
    }
    __syncthreads();

    const int p = pblk * 256 + tid;
    const int t = p >> 12;             // 0..1
    const int s = p & 4095;            // h*64+w
    const int xb = t * 16384 + s;
    const float x0 = x[xb];
    const float x1 = x[xb + 4096];
    const float x2 = x[xb + 8192];
    const float x3 = x[xb + 12288];
    const float a = ((x0 * x0 + x1 * x1) + x2 * x2) + x3 * x3;

    const v2f X0 = {x0, x0}, X1 = {x1, x1}, X2 = {x2, x2}, X3 = {x3, x3};
    const v2f Av = {a, a};
    const v2f M2 = {-2.0f, -2.0f};

    const v2f* exP = (const v2f*)exL;
    const v2f* eyP = (const v2f*)eyL;
    const v2f* ezP = (const v2f*)ezL;
    const v2f* ewP = (const v2f*)ewL;
    const v2f* bP  = (const v2f*)bL;

    float bd = 3.402823466e38f;
    int   bk = 0;

#pragma unroll 2
    for (int q = 0; q < CHUNK / 4; ++q) {      // 4 codes per iteration
        v2f ex0 = exP[2 * q], ex1 = exP[2 * q + 1];
        v2f ey0 = eyP[2 * q], ey1 = eyP[2 * q + 1];
        v2f ez0 = ezP[2 * q], ez1 = ezP[2 * q + 1];
        v2f ew0 = ewP[2 * q], ew1 = ewP[2 * q + 1];
        v2f b0  = bP [2 * q], b1  = bP [2 * q + 1];

        // m = fma(x3,ew, fma(x2,ez, fma(x1,ey, x0*ex)))  (BLAS chain, R1-verified)
        v2f m0 = pk_fma(X3, ew0, pk_fma(X2, ez0, pk_fma(X1, ey0, pk_mul(X0, ex0))));
        v2f m1 = pk_fma(X3, ew1, pk_fma(X2, ez1, pk_fma(X1, ey1, pk_mul(X0, ex1))));
        v2f t0 = pk_add(Av, b0);
        v2f t1 = pk_add(Av, b1);
        // fma(-2,m,t) == (a+b) - fl(2m) bitwise (2m exact, one rounding each)
        v2f d0 = pk_fma(M2, m0, t0);
        v2f d1 = pk_fma(M2, m1, t1);

        // tournament min + first-index equality select == sequential strict-<
        float bd4 = min3f(min3f(bd, d0.x, d0.y), d1.x, d1.y);
        int sel = (d1.x == bd4) ? 2 : 3;
        sel = (d0.y == bd4) ? 1 : sel;
        sel = (d0.x == bd4) ? 0 : sel;
        bool imp = (bd4 != bd);        // tie with old bd -> keep earlier bk
        int cand = kbase + 4 * q + sel;
        bk = imp ? cand : bk;
        bd = bd4;
    }
    dbest[chunk * N_PTS + p] = bd;
    kbest[chunk * N_PTS + p] = bk;
}

// ---------------- K2: merge chunks, gather, z_q_st, per-block loss partial
__global__ __launch_bounds__(64) void k_final(const float* __restrict__ x,
                                              const float* __restrict__ E,
                                              const float* __restrict__ dbest,
                                              const int* __restrict__ kbest,
                                              float* __restrict__ out,
                                              double* __restrict__ partials) {
#pragma clang fp contract(off)
    const int tid = threadIdx.x;
    const int p   = blockIdx.x * 64 + tid;     // 128 blocks x 64 threads
    const int t   = p >> 12;
    const int s   = p & 4095;

    float bd = 3.402823466e38f;
    int   bk = 0;
    for (int c = 0; c < NC; ++c) {             // increasing k ranges
        float d = dbest[c * N_PTS + p];
        int   k = kbest[c * N_PTS + p];
        if (d < bd) { bd = d; bk = k; }        // strict <: earliest chunk kept
    }

    float4 e = ((const float4*)E)[bk];
    float ev[4] = {e.x, e.y, e.z, e.w};
    double ls = 0.0;
    const int xb = t * 16384 + s;
    for (int ch = 0; ch < 4; ++ch) {
        int idx = xb + ch * 4096;
        float xv   = x[idx];
        float diff = ev[ch] - xv;              // fl(z_q - x)
        float sq   = diff * diff;              // fl(diff^2)
        out[idx]   = xv + diff;                // z_q_st = fl(x + fl(z_q - x))
        ls += (double)sq;
    }
    out[32769 + p] = (float)bk;                // codes as float

    // wave-level reduce (block == 1 wave)
    for (int o = 32; o > 0; o >>= 1) ls += __shfl_down(ls, o);
    if (tid == 0) partials[blockIdx.x] = ls;
}

// ---------------- K3: finalize qloss
__global__ void k_loss(const double* __restrict__ partials,
                       float* __restrict__ out) {
#pragma clang fp contract(off)
    if (threadIdx.x == 0 && blockIdx.x == 0) {
        double sum = 0.0;
        for (int i = 0; i < 128; ++i) sum += partials[i];
        float mu = (float)(sum * (1.0 / 32768.0));   // /32768 exact scale
        float q  = mu + 0.1f * mu;                   // mean1 + BETA*mean2 (bitwise equal means)
        out[32768] = q;
    }
}

extern "C" void kernel_launch(void* const* d_in, const int* in_sizes, int n_in,
                              void* d_out, int out_size, void* d_ws, size_t ws_size,
                              hipStream_t stream) {
    const float* x = (const float*)d_in[0];   // (1,2,4,64,64)
    const float* E = (const float*)d_in[1];   // (32768,4)
    float* out = (float*)d_out;               // 40961 floats

    char* ws = (char*)d_ws;
    double* partials = (double*)ws;                              // 1 KB
    float*  dbest    = (float*)(ws + 1024);                      // 1 MB
    int*    kbest    = (int*)  (ws + 1024 + 1048576);            // 1 MB

    dim3 g1(NC, NPB);
    k_dist<<<g1, 256, 0, stream>>>(x, E, dbest, kbest);
    k_final<<<N_PTS / 64, 64, 0, stream>>>(x, E, dbest, kbest, out, partials);
    k_loss<<<1, 64, 0, stream>>>(partials, out);
}